// Round 3
// baseline (1102.034 us; speedup 1.0000x reference)
//
#include <hip/hip_runtime.h>

// GCNCheb on MI355X (round 3): single persistent fused kernel.
// out = x(w0-w2) + Lx(w1-w3) + L^2x*2w2 + L^3x*2w3 + bias.
// Phases: [convert L->bf16, pack x, init out] -> 3x [gemm split-K=8, combine],
// separated by device-scope atomic grid barriers (all 512 WGs co-resident:
// 32 KB LDS -> 5/CU cap; launch_bounds(256,2) -> VGPR<=256 -> >=2/CU).

typedef __bf16 bf16;
typedef bf16 bf16x4 __attribute__((ext_vector_type(4)));
typedef bf16 bf16x8 __attribute__((ext_vector_type(8)));
typedef float f32x4 __attribute__((ext_vector_type(4)));

static_assert(sizeof(bf16x8) == 16, "bf16x8 must be 16B");

#define N_DIM 8192
#define NCOLS 128            // B * F_IN
#define BM 128
#define BK 64
#define SPLITS 8
#define KCHUNK (N_DIM / SPLITS)   // 1024
#define NWG 512
#define NT 256

__device__ inline unsigned short f2bf_bits(float f) {
    bf16 b = (bf16)f;
    return __builtin_bit_cast(unsigned short, b);
}

__device__ inline void load_lds16(const bf16* g, bf16* l) {
    __builtin_amdgcn_global_load_lds(
        (const __attribute__((address_space(1))) void*)g,
        (__attribute__((address_space(3))) void*)l, 16, 0, 0);
}

// ---- barrier counters live in ws (re-poisoned each launch) -> re-zero ----
__global__ void zero_cnt_kernel(int* cnt) {
    if (threadIdx.x < 16) cnt[threadIdx.x] = 0;
}

// device-scope grid barrier; each idx used exactly once per launch
__device__ inline void grid_barrier(int* cnt, int idx) {
    __syncthreads();
    if (threadIdx.x == 0) {
        __threadfence();   // release: publish this WG's global writes
        __hip_atomic_fetch_add(&cnt[idx], 1, __ATOMIC_ACQ_REL,
                               __HIP_MEMORY_SCOPE_AGENT);
        while (__hip_atomic_load(&cnt[idx], __ATOMIC_ACQUIRE,
                                 __HIP_MEMORY_SCOPE_AGENT) < NWG)
            __builtin_amdgcn_s_sleep(2);
        __threadfence();   // acquire: invalidate caches before consuming
    }
    __syncthreads();
}

// ---------------- gemm phase: part[sp] = Lb[rows, kchunk] @ Xb[:, kchunk]^T --
__device__ __attribute__((always_inline)) void gemm_phase(
    const bf16* __restrict__ Lb, const bf16* __restrict__ Xb,
    float* __restrict__ part, bf16* As, bf16* Bs, int wg, int t) {
    const int mt = wg & 63;
    const int sp = wg >> 6;
    const int rbase = mt * BM;
    const size_t kbase = (size_t)sp * KCHUNK;
    const int lane = t & 63;
    const int wave = t >> 6;
    const int wr = wave >> 1, wc = wave & 1;   // 2x2 wave grid, 64x64 out each
    const int lm = lane & 15, kq = lane >> 4;
    const int lrow = lane >> 3;                // 0..7
    const int jb = (lane & 7) ^ lrow;          // swizzled global col block

    f32x4 acc[4][4];
    const f32x4 zero = {0.f, 0.f, 0.f, 0.f};
#pragma unroll
    for (int mi = 0; mi < 4; mi++)
#pragma unroll
        for (int ni = 0; ni < 4; ni++) acc[mi][ni] = zero;

    for (int kk = 0; kk < KCHUNK; kk += BK) {
#pragma unroll
        for (int i = 0; i < 4; i++) {
            const int c = wave * 4 + i;          // 0..15
            const int row = 8 * c + lrow;        // 0..127
            load_lds16(&Lb[(size_t)(rbase + row) * N_DIM + kbase + kk + jb * 8],
                       &As[c * 512]);
            load_lds16(&Xb[(size_t)row * N_DIM + kbase + kk + jb * 8],
                       &Bs[c * 512]);
        }
        __syncthreads();

#pragma unroll
        for (int ks = 0; ks < 2; ks++) {
            bf16x8 af[4], bfr[4];
#pragma unroll
            for (int mi = 0; mi < 4; mi++) {
                int r = wr * 64 + mi * 16 + lm;
                int cb = (kq + 4 * ks) ^ (lm & 7);
                af[mi] = *(const bf16x8*)(&As[r * BK + cb * 8]);
            }
#pragma unroll
            for (int ni = 0; ni < 4; ni++) {
                int r = wc * 64 + ni * 16 + lm;
                int cb = (kq + 4 * ks) ^ (lm & 7);
                bfr[ni] = *(const bf16x8*)(&Bs[r * BK + cb * 8]);
            }
#pragma unroll
            for (int mi = 0; mi < 4; mi++)
#pragma unroll
                for (int ni = 0; ni < 4; ni++)
                    acc[mi][ni] = __builtin_amdgcn_mfma_f32_16x16x32_bf16(
                        af[mi], bfr[ni], acc[mi][ni], 0, 0, 0);
        }
        __syncthreads();
    }

    // epilogue: C/D layout col=lane&15, row=(lane>>4)*4+reg  [m89/m91]
    float* P = part + (size_t)sp * N_DIM * NCOLS;
#pragma unroll
    for (int mi = 0; mi < 4; mi++) {
        int row0 = rbase + wr * 64 + mi * 16 + kq * 4;
#pragma unroll
        for (int ni = 0; ni < 4; ni++) {
            int col = wc * 64 + ni * 16 + lm;
#pragma unroll
            for (int r = 0; r < 4; r++)
                P[(size_t)(row0 + r) * NCOLS + col] = acc[mi][ni][r];
        }
    }
}

// ---------------- combine: Y=sum partials; out += Y.weff; XbNext = bf16(Y^T) --
__device__ __attribute__((always_inline)) void combine_phase(
    const float* __restrict__ part, const float* __restrict__ w,
    float* __restrict__ out, bf16* __restrict__ XbNext,
    float* weff, float* Yt, int pass, int wg, int t) {
    const int n0 = wg * 16;          // 512 WGs x 16 rows

    for (int i = t; i < 2048; i += NT) {
        float v;
        if (pass == 1)      v = w[2048 + i] - w[3 * 2048 + i];
        else if (pass == 2) v = 2.f * w[2 * 2048 + i];
        else                v = 2.f * w[3 * 2048 + i];
        weff[i] = v;
    }
    // phase A: sum SPLITS partials for rows n0..n0+15, transpose into LDS
    for (int s = t; s < 512; s += NT) {
        int row = s >> 5, c4 = s & 31;
        float4 sum = {0.f, 0.f, 0.f, 0.f};
#pragma unroll
        for (int sp = 0; sp < SPLITS; sp++) {
            const float4 v = *(const float4*)(
                &part[(size_t)sp * N_DIM * NCOLS + (size_t)(n0 + row) * NCOLS + c4 * 4]);
            sum.x += v.x; sum.y += v.y; sum.z += v.z; sum.w += v.w;
        }
        Yt[(c4 * 4 + 0) * 17 + row] = sum.x;
        Yt[(c4 * 4 + 1) * 17 + row] = sum.y;
        Yt[(c4 * 4 + 2) * 17 + row] = sum.z;
        Yt[(c4 * 4 + 3) * 17 + row] = sum.w;
    }
    __syncthreads();
    // phase B: bf16 X^T for next pass
    if (pass < 3) {
        int c = t >> 1, half = t & 1;
        union { uint4 u; unsigned short s[8]; } pk;
#pragma unroll
        for (int j = 0; j < 8; j++)
            pk.s[j] = f2bf_bits(Yt[c * 17 + half * 8 + j]);
        *(uint4*)(&XbNext[(size_t)c * N_DIM + n0 + half * 8]) = pk.u;
    }
    // phase C: out[b, n0+n, fo] += sum_fi Y[n][b*32+fi] * weff[fi][fo]
    int b = t >> 6, fo = t & 63;
    for (int n = 0; n < 16; n++) {
        size_t oidx = ((size_t)b * N_DIM + n0 + n) * 64 + fo;
        float acc = out[oidx];
#pragma unroll
        for (int fi = 0; fi < 32; fi++)
            acc += Yt[(b * 32 + fi) * 17 + n] * weff[fi * 64 + fo];
        out[oidx] = acc;
    }
}

// ---------------- the persistent fused kernel ----------------
__global__ __launch_bounds__(256, 2) void fused_kernel(
    const float* __restrict__ L, const float* __restrict__ x,
    const float* __restrict__ w, const float* __restrict__ bias,
    float* __restrict__ out, bf16* __restrict__ Lb,
    bf16* __restrict__ XbA, bf16* __restrict__ XbB,
    float* __restrict__ part, int* __restrict__ cnt) {
    __shared__ alignas(16) unsigned char smem[32768];
    const int wg = blockIdx.x, t = threadIdx.x;

    // ---- setup: convert L fp32->bf16 (grid-stride), pack x -> X0^T ----
    {
        const float4* Lf4 = (const float4*)L;
        const size_t base = (size_t)wg * NT + t;
#pragma unroll 4
        for (int i = 0; i < 128; i++) {
            size_t idx = base + (size_t)i * (NWG * NT);
            float4 v = Lf4[idx];
            bf16x4 p;
            p[0] = (bf16)v.x; p[1] = (bf16)v.y; p[2] = (bf16)v.z; p[3] = (bf16)v.w;
            *(bf16x4*)(Lb + idx * 4) = p;
        }
#pragma unroll
        for (int i = 0; i < 8; i++) {
            size_t g = base + (size_t)i * (NWG * NT);
            int n = (int)(g & 8191), c = (int)(g >> 13);
            int b = c >> 5, fi = c & 31;
            XbA[(size_t)c * N_DIM + n] = (bf16)x[((size_t)b * N_DIM + n) * 32 + fi];
        }
    }
    // ---- init out = bias + x.(w0-w2), rows n0..n0+15, all b ----
    {
        float* weff0 = (float*)smem;
        float* xs = (float*)(smem + 8192);
        const int n0 = wg * 16;
        for (int i = t; i < 2048; i += NT) weff0[i] = w[i] - w[2 * 2048 + i];
        for (int i = t; i < 2048; i += NT) {
            int b = i >> 9, lr = (i >> 5) & 15, fi = i & 31;
            xs[i] = x[((size_t)b * N_DIM + n0 + lr) * 32 + fi];
        }
        __syncthreads();
        int b = t >> 6, fo = t & 63;
        for (int n = 0; n < 16; n++) {
            float acc = bias[(size_t)(n0 + n) * 64 + fo];
#pragma unroll
            for (int fi = 0; fi < 32; fi++)
                acc += xs[b * 512 + n * 32 + fi] * weff0[fi * 64 + fo];
            out[((size_t)b * N_DIM + n0 + n) * 64 + fo] = acc;
        }
    }
    grid_barrier(cnt, 0);

    bf16* As = (bf16*)smem;
    bf16* Bs = (bf16*)(smem + 16384);
    float* weff = (float*)smem;
    float* Yt = (float*)(smem + 8192);

    // pass 1
    gemm_phase(Lb, XbA, part, As, Bs, wg, t);
    grid_barrier(cnt, 1);
    combine_phase(part, w, out, XbB, weff, Yt, 1, wg, t);
    grid_barrier(cnt, 2);
    // pass 2
    gemm_phase(Lb, XbB, part, As, Bs, wg, t);
    grid_barrier(cnt, 3);
    combine_phase(part, w, out, XbA, weff, Yt, 2, wg, t);
    grid_barrier(cnt, 4);
    // pass 3
    gemm_phase(Lb, XbA, part, As, Bs, wg, t);
    grid_barrier(cnt, 5);
    combine_phase(part, w, out, XbA, weff, Yt, 3, wg, t);
}

extern "C" void kernel_launch(void* const* d_in, const int* in_sizes, int n_in,
                              void* d_out, int out_size, void* d_ws, size_t ws_size,
                              hipStream_t stream) {
    const float* x    = (const float*)d_in[0];   // [4,8192,32]
    const float* L    = (const float*)d_in[1];   // [8192,8192]
    const float* w    = (const float*)d_in[2];   // [4,32,64]
    const float* bias = (const float*)d_in[3];   // [1,8192,64]
    float* out = (float*)d_out;                  // [4,8192,64]

    char* ws = (char*)d_ws;                          // ws_size ~1 GB (observed)
    bf16* Lb    = (bf16*)ws;                         // 128 MB
    bf16* XbA   = (bf16*)(ws + (128ull << 20));      // 2 MB
    bf16* XbB   = (bf16*)(ws + (130ull << 20));      // 2 MB
    float* part = (float*)(ws + (132ull << 20));     // 32 MB
    int* cnt    = (int*)(ws + (164ull << 20));       // 64 B barrier counters

    zero_cnt_kernel<<<1, 64, 0, stream>>>(cnt);
    fused_kernel<<<NWG, NT, 0, stream>>>(L, x, w, bias, out, Lb, XbA, XbB, part, cnt);
}

// Round 4
// 551.587 us; speedup vs baseline: 1.9979x; 1.9979x over previous
//
#include <hip/hip_runtime.h>

// GCNCheb on MI355X (round 4): separate kernels (fusion regressed 2x in r3).
// New GEMM: A (L) streamed direct global->register (no barrier dependency,
// deep MLP); B (Xb, 2 MB) staged to LDS once per 256-k sub-chunk (2 barriers
// per 256 k instead of vmcnt(0)-drain per 64 k). 16x16x32 bf16 MFMA with
// m91-verified A and C/D layouts. Split-K=8 -> part, then combine.

typedef __bf16 bf16;
typedef bf16 bf16x4 __attribute__((ext_vector_type(4)));
typedef bf16 bf16x8 __attribute__((ext_vector_type(8)));
typedef float f32x4 __attribute__((ext_vector_type(4)));

static_assert(sizeof(bf16x8) == 16, "bf16x8 must be 16B");

#define N_DIM 8192
#define NCOLS 128            // B * F_IN
#define BM 128               // rows per WG (4 waves x 32 rows)
#define SPLITS 8
#define KCHUNK (N_DIM / SPLITS)   // 1024
#define SUBK 256             // k per staged B sub-chunk (LDS 64 KB)

__device__ inline unsigned short f2bf_bits(float f) {
    bf16 b = (bf16)f;
    return __builtin_bit_cast(unsigned short, b);
}

__device__ inline void load_lds16(const bf16* g, bf16* l) {
    __builtin_amdgcn_global_load_lds(
        (const __attribute__((address_space(1))) void*)g,
        (__attribute__((address_space(3))) void*)l, 16, 0, 0);
}

// ---------------- L fp32 -> bf16 ----------------
__global__ __launch_bounds__(256) void convert_L_kernel(
    const float* __restrict__ L, bf16* __restrict__ Lb) {
    size_t i = ((size_t)blockIdx.x * 256 + threadIdx.x) * 4;
    const float4 v = *(const float4*)(L + i);
    bf16x4 p;
    p[0] = (bf16)v.x; p[1] = (bf16)v.y; p[2] = (bf16)v.z; p[3] = (bf16)v.w;
    *(bf16x4*)(Lb + i) = p;
}

// ---------------- pack x -> X0^T [128][8192] bf16 ----------------
__global__ __launch_bounds__(256) void pack_x_kernel(
    const float* __restrict__ x, bf16* __restrict__ Xb0) {
    int g = blockIdx.x * 256 + threadIdx.x;    // 0 .. 128*8192
    int n = g & 8191;
    int c = g >> 13;          // 0..127 ; c = b*32 + fi
    int b = c >> 5, fi = c & 31;
    Xb0[(size_t)c * N_DIM + n] = (bf16)x[((size_t)b * N_DIM + n) * 32 + fi];
}

// ---------------- out = bias + x . (w0 - w2)  (pure fp32) ----------------
__global__ __launch_bounds__(256) void init_out_kernel(
    const float* __restrict__ x, const float* __restrict__ w,
    const float* __restrict__ bias, float* __restrict__ out) {
    __shared__ float weff0[32 * 64];
    __shared__ float xs[16 * 32];
    int t = threadIdx.x;
    for (int i = t; i < 2048; i += 256) weff0[i] = w[i] - w[2 * 2048 + i];
    int r0 = blockIdx.x * 16;   // flat row index r = b*8192 + n, 16 rows/block
    for (int i = t; i < 512; i += 256) {
        int lr = i >> 5, fi = i & 31;
        xs[i] = x[(size_t)(r0 + lr) * 32 + fi];
    }
    __syncthreads();
    for (int i = t; i < 1024; i += 256) {
        int lr = i >> 6, fo = i & 63;
        int r = r0 + lr;
        float acc = bias[(size_t)(r & 8191) * 64 + fo];
#pragma unroll
        for (int fi = 0; fi < 32; fi++)
            acc += xs[lr * 32 + fi] * weff0[fi * 64 + fo];
        out[(size_t)r * 64 + fo] = acc;
    }
}

// ---------------- split-K GEMM, barrier-free K-loop ----------------
// part[sp] += Lb[rbase..+128, kchunk] @ Xb[:, kchunk]^T
// A: direct 16B global loads per lane (MFMA A-frag: m=lane&15, k=(lane>>4)*8+j).
// B: LDS-staged per SUBK with 16B-block XOR swizzle (phys_kb = log_kb ^ (col&7)).
__global__ __launch_bounds__(256, 2) void gemm_kernel(
    const bf16* __restrict__ Lb, const bf16* __restrict__ Xb,
    float* __restrict__ part) {
    __shared__ bf16 Bs[NCOLS * SUBK];   // 64 KB -> 2 WG/CU

    const int mt = blockIdx.x;           // 0..63
    const int sp = blockIdx.y;           // 0..SPLITS-1
    const int rbase = mt * BM;
    const int t = threadIdx.x;
    const int lane = t & 63;
    const int wave = t >> 6;             // wave handles rows wave*32..+32
    const int lm = lane & 15, kq = lane >> 4;
    // staging: chunk c = wave*16+i is 1 KB covering cols 2c,2c+1.
    // lane -> col 2c+(lane>>5), phys 16B-block lane&31; LDS dst = base+lane*16.
    const int scol2 = lane >> 5;
    const int skb = lane & 31;

    f32x4 acc[2][8];
    const f32x4 zero = {0.f, 0.f, 0.f, 0.f};
#pragma unroll
    for (int mi = 0; mi < 2; mi++)
#pragma unroll
        for (int ni = 0; ni < 8; ni++) acc[mi][ni] = zero;

    const bf16* Arow0 = Lb + (size_t)(rbase + wave * 32 + lm) * N_DIM;
    const bf16* Arow1 = Lb + (size_t)(rbase + wave * 32 + 16 + lm) * N_DIM;

    for (int sc = 0; sc < KCHUNK / SUBK; sc++) {   // 4 sub-chunks
        const size_t kb = (size_t)sp * KCHUNK + sc * SUBK;
        // ---- stage B sub-chunk: 64 chunks of 1 KB, swizzled source ----
#pragma unroll
        for (int i = 0; i < 16; i++) {
            int c = wave * 16 + i;
            int col = 2 * c + scol2;
            int klog = skb ^ (col & 7);
            load_lds16(&Xb[(size_t)col * N_DIM + kb + klog * 8], &Bs[c * 512]);
        }
        __syncthreads();   // B tile ready (drains A-stream too; acceptable 1/256k)

        // ---- 8 k-steps of 32, no barriers ----
#pragma unroll 4
        for (int st = 0; st < 8; st++) {
            const size_t ko = kb + st * 32 + kq * 8;
            bf16x8 a0 = *(const bf16x8*)(Arow0 + ko);
            bf16x8 a1 = *(const bf16x8*)(Arow1 + ko);
#pragma unroll
            for (int ni = 0; ni < 8; ni++) {
                int col = ni * 16 + lm;
                int kphys = (st * 4 + kq) ^ (col & 7);
                bf16x8 bfrag = *(const bf16x8*)(&Bs[col * SUBK + kphys * 8]);
                acc[0][ni] = __builtin_amdgcn_mfma_f32_16x16x32_bf16(
                    a0, bfrag, acc[0][ni], 0, 0, 0);
                acc[1][ni] = __builtin_amdgcn_mfma_f32_16x16x32_bf16(
                    a1, bfrag, acc[1][ni], 0, 0, 0);
            }
        }
        __syncthreads();   // reads done before next stage overwrites
    }

    // epilogue: C/D layout col=lane&15, row=(lane>>4)*4+reg  [m89/m91]
    float* P = part + (size_t)sp * N_DIM * NCOLS;
#pragma unroll
    for (int mi = 0; mi < 2; mi++) {
        int row0 = rbase + wave * 32 + mi * 16 + kq * 4;
#pragma unroll
        for (int ni = 0; ni < 8; ni++) {
            int col = ni * 16 + lm;
#pragma unroll
            for (int r = 0; r < 4; r++)
                P[(size_t)(row0 + r) * NCOLS + col] = acc[mi][ni][r];
        }
    }
}

// ---------------- combine: Y = sum partials; out += Y . w_eff[pass]; XbNext = bf16(Y^T) ----
__global__ __launch_bounds__(256) void combine_kernel(
    const float* __restrict__ part, const float* __restrict__ w,
    float* __restrict__ out, bf16* __restrict__ XbNext, int pass) {
    __shared__ float Yt[128 * 66];     // transposed tile [col][row], pad 66
    __shared__ float weff[32 * 64];
    int t = threadIdx.x;
    int n0 = blockIdx.x * 64;

    for (int i = t; i < 2048; i += 256) {
        float v;
        if (pass == 1)      v = w[2048 + i] - w[3 * 2048 + i];
        else if (pass == 2) v = 2.f * w[2 * 2048 + i];
        else                v = 2.f * w[3 * 2048 + i];
        weff[i] = v;
    }
    // phase A: sum SPLITS partials, store transposed into LDS
    for (int slot = t; slot < 2048; slot += 256) {
        int row = slot >> 5;       // 0..63
        int c4 = slot & 31;        // float4 col group
        float4 s = {0.f, 0.f, 0.f, 0.f};
#pragma unroll
        for (int sp = 0; sp < SPLITS; sp++) {
            const float4 v = *(const float4*)(
                &part[(size_t)sp * N_DIM * NCOLS + (size_t)(n0 + row) * NCOLS + c4 * 4]);
            s.x += v.x; s.y += v.y; s.z += v.z; s.w += v.w;
        }
        Yt[(c4 * 4 + 0) * 66 + row] = s.x;
        Yt[(c4 * 4 + 1) * 66 + row] = s.y;
        Yt[(c4 * 4 + 2) * 66 + row] = s.z;
        Yt[(c4 * 4 + 3) * 66 + row] = s.w;
    }
    __syncthreads();
    // phase B: bf16 X^T for next pass
    if (pass < 3) {
        int c = t >> 1;
        int nh = (t & 1) * 32;
#pragma unroll
        for (int v4 = 0; v4 < 4; v4++) {
            union { uint4 u; unsigned short s[8]; } pk;
#pragma unroll
            for (int j = 0; j < 8; j++)
                pk.s[j] = f2bf_bits(Yt[c * 66 + nh + v4 * 8 + j]);
            *(uint4*)(&XbNext[(size_t)c * N_DIM + n0 + nh + v4 * 8]) = pk.u;
        }
    }
    // phase C: out[b, n0+n, fo] += sum_fi Y[n, b*32+fi] * weff[fi][fo]
    int b = t >> 6, fo = t & 63;
    for (int n = 0; n < 64; n++) {
        size_t oidx = ((size_t)b * N_DIM + n0 + n) * 64 + fo;
        float accv = out[oidx];
#pragma unroll
        for (int fi = 0; fi < 32; fi++)
            accv += Yt[(b * 32 + fi) * 66 + n] * weff[fi * 64 + fo];
        out[oidx] = accv;
    }
}

extern "C" void kernel_launch(void* const* d_in, const int* in_sizes, int n_in,
                              void* d_out, int out_size, void* d_ws, size_t ws_size,
                              hipStream_t stream) {
    const float* x    = (const float*)d_in[0];   // [4,8192,32]
    const float* L    = (const float*)d_in[1];   // [8192,8192]
    const float* w    = (const float*)d_in[2];   // [4,32,64]
    const float* bias = (const float*)d_in[3];   // [1,8192,64]
    float* out = (float*)d_out;                  // [4,8192,64]

    char* ws = (char*)d_ws;                          // ws_size ~1 GB (observed)
    bf16* Lb   = (bf16*)ws;                          // 128 MB bf16 L
    bf16* XbA  = (bf16*)(ws + (128ull << 20));       // 2 MB  (X^T bf16)
    bf16* XbB  = (bf16*)(ws + (130ull << 20));       // 2 MB
    float* part = (float*)(ws + (132ull << 20));     // SPLITS * 4 MB = 32 MB

    convert_L_kernel<<<(N_DIM * (size_t)N_DIM) / (4 * 256), 256, 0, stream>>>(L, Lb);
    pack_x_kernel<<<(NCOLS * N_DIM) / 256, 256, 0, stream>>>(x, XbA);
    init_out_kernel<<<(4 * N_DIM) / 16, 256, 0, stream>>>(x, w, bias, out);

    dim3 ggrid(N_DIM / BM, SPLITS);   // 64 x 8 = 512 WGs, 2/CU
    // pass 1: Y = L x
    gemm_kernel<<<ggrid, 256, 0, stream>>>(Lb, XbA, part);
    combine_kernel<<<N_DIM / 64, 256, 0, stream>>>(part, w, out, XbB, 1);
    // pass 2: Y = L^2 x
    gemm_kernel<<<ggrid, 256, 0, stream>>>(Lb, XbB, part);
    combine_kernel<<<N_DIM / 64, 256, 0, stream>>>(part, w, out, XbA, 2);
    // pass 3: Y = L^3 x
    gemm_kernel<<<ggrid, 256, 0, stream>>>(Lb, XbA, part);
    combine_kernel<<<N_DIM / 64, 256, 0, stream>>>(part, w, out, XbA, 3);
}